// Round 1
// baseline (69.152 us; speedup 1.0000x reference)
//
#include <hip/hip_runtime.h>

// MMD loss: mean(delta @ delta.T) == ||colsum(source - target)||^2 / N^2.
// Reduces O(N^2 D) matmul to one O(N D) streaming reduction (64 MiB read).

#define MMD_N 8192
#define MMD_D 1024
#define COLSUM_BLOCKS 512

__global__ __launch_bounds__(256) void mmd_zero_ws(float* __restrict__ ws) {
    // 256 threads x float4 = 1024 floats
    reinterpret_cast<float4*>(ws)[threadIdx.x] = make_float4(0.f, 0.f, 0.f, 0.f);
}

__global__ __launch_bounds__(256) void mmd_colsum(const float* __restrict__ src,
                                                  const float* __restrict__ tgt,
                                                  float* __restrict__ ws) {
    const int tid = threadIdx.x;           // owns columns [4*tid, 4*tid+3]
    const float4* s4 = reinterpret_cast<const float4*>(src);
    const float4* t4 = reinterpret_cast<const float4*>(tgt);
    float4 acc = make_float4(0.f, 0.f, 0.f, 0.f);
    // Each block handles rows bid, bid+512, ... (16 rows). Each row access by a
    // wave is 64 lanes x 16 B contiguous -> fully coalesced.
    for (int row = blockIdx.x; row < MMD_N; row += COLSUM_BLOCKS) {
        const int idx = row * (MMD_D / 4) + tid;
        float4 s = s4[idx];
        float4 t = t4[idx];
        acc.x += s.x - t.x;
        acc.y += s.y - t.y;
        acc.z += s.z - t.z;
        acc.w += s.w - t.w;
    }
    atomicAdd(&ws[4 * tid + 0], acc.x);
    atomicAdd(&ws[4 * tid + 1], acc.y);
    atomicAdd(&ws[4 * tid + 2], acc.z);
    atomicAdd(&ws[4 * tid + 3], acc.w);
}

__global__ __launch_bounds__(256) void mmd_finish(const float* __restrict__ ws,
                                                  float* __restrict__ out) {
    const int tid = threadIdx.x;
    float4 v = reinterpret_cast<const float4*>(ws)[tid];
    float sq = v.x * v.x + v.y * v.y + v.z * v.z + v.w * v.w;
    // wave64 reduce
    for (int off = 32; off > 0; off >>= 1)
        sq += __shfl_down(sq, off, 64);
    __shared__ float part[4];
    if ((tid & 63) == 0) part[tid >> 6] = sq;
    __syncthreads();
    if (tid == 0) {
        float tot = part[0] + part[1] + part[2] + part[3];
        out[0] = tot / ((float)MMD_N * (float)MMD_N);
    }
}

extern "C" void kernel_launch(void* const* d_in, const int* in_sizes, int n_in,
                              void* d_out, int out_size, void* d_ws, size_t ws_size,
                              hipStream_t stream) {
    const float* src = (const float*)d_in[0];
    const float* tgt = (const float*)d_in[1];
    float* out = (float*)d_out;
    float* ws = (float*)d_ws;  // needs MMD_D floats = 4 KiB

    mmd_zero_ws<<<1, 256, 0, stream>>>(ws);
    mmd_colsum<<<COLSUM_BLOCKS, 256, 0, stream>>>(src, tgt, ws);
    mmd_finish<<<1, 256, 0, stream>>>(ws, out);
}

// Round 2
// 53.080 us; speedup vs baseline: 1.3028x; 1.3028x over previous
//
#include <hip/hip_runtime.h>

// MMD loss: mean(delta @ delta.T) == ||colsum(source - target)||^2 / N^2.
// O(N*D) streaming reduction (64 MiB read). Latency-hiding version:
// 2048 blocks (full occupancy), 8 loads in flight/thread, 8x-replicated
// accumulators to cut atomic contention 2048-way -> 256-way.

#define MMD_N 8192
#define MMD_D 1024
#define COLSUM_BLOCKS 2048
#define ROWS_PER_BLOCK 4   // COLSUM_BLOCKS * ROWS_PER_BLOCK == MMD_N
#define NREP 8             // replicated accumulator arrays

__global__ __launch_bounds__(256) void mmd_zero_ws(float* __restrict__ ws) {
    // zero NREP * MMD_D floats = 8192 floats = 2048 float4
    float4* w4 = reinterpret_cast<float4*>(ws);
#pragma unroll
    for (int i = 0; i < NREP; ++i)
        w4[i * 256 + threadIdx.x] = make_float4(0.f, 0.f, 0.f, 0.f);
}

__global__ __launch_bounds__(256) void mmd_colsum(const float* __restrict__ src,
                                                  const float* __restrict__ tgt,
                                                  float* __restrict__ ws) {
    const int tid = threadIdx.x;  // owns columns [4*tid, 4*tid+3]
    const int row0 = blockIdx.x * ROWS_PER_BLOCK;
    const float4* s4 = reinterpret_cast<const float4*>(src);
    const float4* t4 = reinterpret_cast<const float4*>(tgt);

    // Issue all 8 loads up front (compiler schedules them in flight together).
    float4 s[ROWS_PER_BLOCK], t[ROWS_PER_BLOCK];
#pragma unroll
    for (int r = 0; r < ROWS_PER_BLOCK; ++r) {
        const int idx = (row0 + r) * (MMD_D / 4) + tid;
        s[r] = s4[idx];
        t[r] = t4[idx];
    }
    float4 acc = make_float4(0.f, 0.f, 0.f, 0.f);
#pragma unroll
    for (int r = 0; r < ROWS_PER_BLOCK; ++r) {
        acc.x += s[r].x - t[r].x;
        acc.y += s[r].y - t[r].y;
        acc.z += s[r].z - t[r].z;
        acc.w += s[r].w - t[r].w;
    }
    float* wrep = ws + (blockIdx.x & (NREP - 1)) * MMD_D;
    atomicAdd(&wrep[4 * tid + 0], acc.x);
    atomicAdd(&wrep[4 * tid + 1], acc.y);
    atomicAdd(&wrep[4 * tid + 2], acc.z);
    atomicAdd(&wrep[4 * tid + 3], acc.w);
}

__global__ __launch_bounds__(256) void mmd_finish(const float* __restrict__ ws,
                                                  float* __restrict__ out) {
    const int tid = threadIdx.x;
    const float4* w4 = reinterpret_cast<const float4*>(ws);
    float4 tot = make_float4(0.f, 0.f, 0.f, 0.f);
#pragma unroll
    for (int i = 0; i < NREP; ++i) {
        float4 v = w4[i * 256 + tid];
        tot.x += v.x; tot.y += v.y; tot.z += v.z; tot.w += v.w;
    }
    float sq = tot.x * tot.x + tot.y * tot.y + tot.z * tot.z + tot.w * tot.w;
    // wave64 reduce
    for (int off = 32; off > 0; off >>= 1)
        sq += __shfl_down(sq, off, 64);
    __shared__ float part[4];
    if ((tid & 63) == 0) part[tid >> 6] = sq;
    __syncthreads();
    if (tid == 0) {
        float totsq = part[0] + part[1] + part[2] + part[3];
        out[0] = totsq / ((float)MMD_N * (float)MMD_N);
    }
}

extern "C" void kernel_launch(void* const* d_in, const int* in_sizes, int n_in,
                              void* d_out, int out_size, void* d_ws, size_t ws_size,
                              hipStream_t stream) {
    const float* src = (const float*)d_in[0];
    const float* tgt = (const float*)d_in[1];
    float* out = (float*)d_out;
    float* ws = (float*)d_ws;  // needs NREP * MMD_D floats = 32 KiB

    mmd_zero_ws<<<1, 256, 0, stream>>>(ws);
    mmd_colsum<<<COLSUM_BLOCKS, 256, 0, stream>>>(src, tgt, ws);
    mmd_finish<<<1, 256, 0, stream>>>(ws, out);
}

// Round 3
// 25.921 us; speedup vs baseline: 2.6678x; 2.0478x over previous
//
#include <hip/hip_runtime.h>

// MMD loss: mean(delta @ delta.T) == ||colsum(source - target)||^2 / N^2.
// O(N*D) streaming reduction (67 MB read).
// R2 lesson: every global atomicAdd write-throughs 16 B to HBM (WRITE_SIZE
// == n_atomics*16B) and the atomic service rate (~1 TB/s) dominated.
// This version cuts atomics 8x: 256 blocks x 1024 threads, 32 rows/block,
// LDS cross-team reduce -> 1024 atomics/block -> 262K total (~4 MB).

#define MMD_N 8192
#define MMD_D 1024
#define NREP 16          // replicated accumulator arrays (16-way contention)
#define CS_BLOCKS 256    // 1 block/CU
#define CS_THREADS 1024  // 16 waves/CU
#define TEAMS 4
#define ROWS_PER_TEAM 8  // 4 teams * 8 rows = 32 rows/block; 256*32 = 8192

__global__ __launch_bounds__(256) void mmd_zero_ws(float* __restrict__ ws) {
    // zero NREP * MMD_D floats = 16384 floats = 64 KiB
    float4* w4 = reinterpret_cast<float4*>(ws);
#pragma unroll
    for (int i = 0; i < NREP; ++i)
        w4[i * 256 + threadIdx.x] = make_float4(0.f, 0.f, 0.f, 0.f);
}

__global__ __launch_bounds__(CS_THREADS) void mmd_colsum(const float* __restrict__ src,
                                                         const float* __restrict__ tgt,
                                                         float* __restrict__ ws) {
    const int tid  = threadIdx.x;
    const int team = tid >> 8;        // 0..3: which row-team
    const int col4 = tid & 255;       // float4 column index (owns cols 4*col4..+3)
    const int row0 = blockIdx.x * (TEAMS * ROWS_PER_TEAM) + team * ROWS_PER_TEAM;
    const float4* s4 = reinterpret_cast<const float4*>(src);
    const float4* t4 = reinterpret_cast<const float4*>(tgt);

    float4 s[ROWS_PER_TEAM], t[ROWS_PER_TEAM];
#pragma unroll
    for (int r = 0; r < ROWS_PER_TEAM; ++r) {
        const int idx = (row0 + r) * (MMD_D / 4) + col4;
        s[r] = s4[idx];
        t[r] = t4[idx];
    }
    float4 acc = make_float4(0.f, 0.f, 0.f, 0.f);
#pragma unroll
    for (int r = 0; r < ROWS_PER_TEAM; ++r) {
        acc.x += s[r].x - t[r].x;
        acc.y += s[r].y - t[r].y;
        acc.z += s[r].z - t[r].z;
        acc.w += s[r].w - t[r].w;
    }

    // cross-team reduce in LDS: 4 teams x 256 float4 = 16 KiB
    __shared__ float4 red[TEAMS][256];
    red[team][col4] = acc;
    __syncthreads();
    if (tid < 256) {
        float4 a = red[0][tid];
        float4 b = red[1][tid];
        float4 c = red[2][tid];
        float4 d = red[3][tid];
        float4 tot;
        tot.x = (a.x + b.x) + (c.x + d.x);
        tot.y = (a.y + b.y) + (c.y + d.y);
        tot.z = (a.z + b.z) + (c.z + d.z);
        tot.w = (a.w + b.w) + (c.w + d.w);
        float* wrep = ws + (blockIdx.x & (NREP - 1)) * MMD_D;
        atomicAdd(&wrep[4 * tid + 0], tot.x);
        atomicAdd(&wrep[4 * tid + 1], tot.y);
        atomicAdd(&wrep[4 * tid + 2], tot.z);
        atomicAdd(&wrep[4 * tid + 3], tot.w);
    }
}

__global__ __launch_bounds__(256) void mmd_finish(const float* __restrict__ ws,
                                                  float* __restrict__ out) {
    const int tid = threadIdx.x;
    const float4* w4 = reinterpret_cast<const float4*>(ws);
    float4 tot = make_float4(0.f, 0.f, 0.f, 0.f);
#pragma unroll
    for (int i = 0; i < NREP; ++i) {
        float4 v = w4[i * 256 + tid];
        tot.x += v.x; tot.y += v.y; tot.z += v.z; tot.w += v.w;
    }
    float sq = tot.x * tot.x + tot.y * tot.y + tot.z * tot.z + tot.w * tot.w;
    for (int off = 32; off > 0; off >>= 1)
        sq += __shfl_down(sq, off, 64);
    __shared__ float part[4];
    if ((tid & 63) == 0) part[tid >> 6] = sq;
    __syncthreads();
    if (tid == 0) {
        float totsq = part[0] + part[1] + part[2] + part[3];
        out[0] = totsq / ((float)MMD_N * (float)MMD_N);
    }
}

extern "C" void kernel_launch(void* const* d_in, const int* in_sizes, int n_in,
                              void* d_out, int out_size, void* d_ws, size_t ws_size,
                              hipStream_t stream) {
    const float* src = (const float*)d_in[0];
    const float* tgt = (const float*)d_in[1];
    float* out = (float*)d_out;
    float* ws = (float*)d_ws;  // needs NREP * MMD_D floats = 64 KiB

    mmd_zero_ws<<<1, 256, 0, stream>>>(ws);
    mmd_colsum<<<CS_BLOCKS, CS_THREADS, 0, stream>>>(src, tgt, ws);
    mmd_finish<<<1, 256, 0, stream>>>(ws, out);
}